// Round 4
// baseline (901.633 us; speedup 1.0000x reference)
//
#include <hip/hip_runtime.h>

#define SEQ   784
#define NTT   49            // 49 time tiles of 16
#define PADT  16            // front zero pad rows (max dilation 16)
#define NROW  (PADT + SEQ)  // 800
#define HSTR  40            // bf16 elements per t-row (32 + 8 pad)
#define NWAVE 8
#define BLK   (NWAVE * 64)
#define LDS_SHORTS (2 * NROW * HSTR)        // 64000
#define LDS_BYTES  (LDS_SHORTS * 2)         // 128000 B

typedef __attribute__((ext_vector_type(8))) short  short8;
typedef __attribute__((ext_vector_type(4))) short  short4v;
typedef __attribute__((ext_vector_type(4))) float  float4v;

__device__ __forceinline__ float bf2f(unsigned short u) {
    union { unsigned int i; float f; } v; v.i = ((unsigned int)u) << 16; return v.f;
}
__device__ __forceinline__ unsigned short f2bf(float f) {
    union { float f; unsigned int i; } v; v.f = f;
    unsigned int r = v.i + 0x7FFFu + ((v.i >> 16) & 1u);   // RNE
    return (unsigned short)(r >> 16);
}
// tanh(a)*sigmoid(b), clamped so no intermediate can reach inf.
__device__ __forceinline__ float gate_fn(float a, float b) {
    a = fminf(fmaxf(a, -12.f), 12.f);
    b = fminf(fmaxf(b, -12.f), 12.f);
    float ta = __builtin_amdgcn_exp2f(-2.885390082f * a);   // e^{-2a}
    float tb = __builtin_amdgcn_exp2f(-1.442695041f * b);   // e^{-b}
    return (1.0f - ta) * __builtin_amdgcn_rcpf((1.0f + ta) * (1.0f + tb));
}
__device__ __forceinline__ unsigned int pack2(unsigned short lo, unsigned short hi) {
    return (unsigned int)lo | ((unsigned int)hi << 16);
}

__global__ void __launch_bounds__(BLK) wavenet_kernel(
    const float* __restrict__ x,
    const float* __restrict__ w_causal,
    const float* __restrict__ b_causal,
    const float* __restrict__ w_dil,
    const float* __restrict__ b_dil,
    const float* __restrict__ w_res,
    const float* __restrict__ b_res,
    const float* __restrict__ w_out,
    const float* __restrict__ b_out,
    float* __restrict__ out)
{
    extern __shared__ unsigned short lds[];
    unsigned short* H0 = lds;                       // [NROW][HSTR] bf16
    unsigned short* H1 = lds + NROW * HSTR;
    // x staged as fp32 in H1 data rows (rows 16..55); dead after causal conv.
    // Layer 0 rewrites H1 data cols 0..31; leftover garbage sits only in pad
    // cols 32..39 of rows 16..55, which no MFMA/B-frag/h load ever touches.
    float* XS = (float*)(H1 + PADT * HSTR);

    const int tid = threadIdx.x;
    const int b   = blockIdx.x;

    // ---- zero ALL LDS ----
    {
        unsigned int* p = (unsigned int*)lds;
        for (int i = tid; i < LDS_SHORTS / 2; i += BLK) p[i] = 0u;
    }
    __syncthreads();

    // ---- stage x (fp32) ----
    for (int t = tid; t < SEQ; t += BLK) XS[t] = x[b * SEQ + t];
    __syncthreads();

    // ---- causal conv: h0[o][t] = wc0[o]*x[t-2] + wc1[o]*x[t-1] + bc[o] ----
    {
        int o = tid & 31;                           // invariant under += BLK
        float wc0 = w_causal[o * 2 + 0];
        float wc1 = w_causal[o * 2 + 1];
        float bc  = b_causal[o];
        for (int idx = tid; idx < SEQ * 32; idx += BLK) {
            int t = idx >> 5;
            float v = bc;
            if (t >= 2) v += wc0 * XS[t - 2];
            if (t >= 1) v += wc1 * XS[t - 1];
            H0[(PADT + t) * HSTR + o] = f2bf(v);
        }
    }
    __syncthreads();

    const int lane = tid & 63;
    const int wave = tid >> 6;
    const int m    = lane & 15;   // A-row / B-col / D-col
    const int q    = lane >> 4;   // quad

    const int dil[10] = {1, 2, 4, 8, 16, 1, 2, 4, 8, 16};

    for (int L = 0; L < 10; ++L) {
        unsigned short* src = (L & 1) ? H1 : H0;
        unsigned short* dst = (L & 1) ? H0 : H1;
        const int d = dil[L];

        // A-frags for dilated conv (fp32 global -> bf16 regs): 4 row-tiles x 2 taps
        short8 WA[4][2];
        for (int rt = 0; rt < 4; ++rt)
            for (int tp = 0; tp < 2; ++tp) {
                short8 f;
                int base = ((L * 64 + rt * 16 + m) * 32 + q * 8) * 2 + tp;
                #pragma unroll
                for (int j = 0; j < 8; ++j) f[j] = (short)f2bf(w_dil[base + 2 * j]);
                WA[rt][tp] = f;
            }
        // A-frags for residual proj
        short8 WR[2];
        for (int rt = 0; rt < 2; ++rt) {
            const float* p = w_res + (L * 32 + rt * 16 + m) * 32 + q * 8;
            short8 f;
            #pragma unroll
            for (int j = 0; j < 8; ++j) f[j] = (short)f2bf(p[j]);
            WR[rt] = f;
        }
        float BD[4][4], BR[2][4];
        #pragma unroll
        for (int rt = 0; rt < 4; ++rt)
            #pragma unroll
            for (int r = 0; r < 4; ++r)
                BD[rt][r] = b_dil[L * 64 + rt * 16 + q * 4 + r];
        #pragma unroll
        for (int rt = 0; rt < 2; ++rt)
            #pragma unroll
            for (int r = 0; r < 4; ++r)
                BR[rt][r] = b_res[L * 32 + rt * 16 + q * 4 + r];

        for (int tt = wave; tt < NTT; tt += NWAVE) {
            const int t0   = tt * 16;
            const int rowu = PADT + t0 + m;
            const short8 Bs = *(const short8*)(src + (rowu - d) * HSTR + q * 8);
            const short8 Bu = *(const short8*)(src + rowu * HSTR + q * 8);

            // Z = W0*H_shift + W1*H  (64x16 tile as 4 row-tiles)
            float4v acc[4];
            #pragma unroll
            for (int rt = 0; rt < 4; ++rt) {
                float4v a = {0.f, 0.f, 0.f, 0.f};
                a = __builtin_amdgcn_mfma_f32_16x16x32_bf16(WA[rt][0], Bs, a, 0, 0, 0);
                a = __builtin_amdgcn_mfma_f32_16x16x32_bf16(WA[rt][1], Bu, a, 0, 0, 0);
                acc[rt] = a;
            }
            // gate: tanh(ch 0..31) * sigmoid(ch 32..63); C-layout (ch=q*4+r, t=m)
            unsigned short gv0[4], gv1[4];
            #pragma unroll
            for (int r = 0; r < 4; ++r) {
                gv0[r] = f2bf(gate_fn(acc[0][r] + BD[0][r], acc[2][r] + BD[2][r])); // ch q*4+r
                gv1[r] = f2bf(gate_fn(acc[1][r] + BD[1][r], acc[3][r] + BD[3][r])); // ch 16+q*4+r
            }
            // register transpose C-layout -> B-layout via shuffles (verified per-quad):
            int P0 = (int)pack2(gv0[0], gv0[1]);
            int P1 = (int)pack2(gv0[2], gv0[3]);
            int P2 = (int)pack2(gv1[0], gv1[1]);
            int P3 = (int)pack2(gv1[2], gv1[3]);
            const int sel = q & 1, hi = q >> 1;
            const int L1 = 32 * sel + m, L2 = L1 + 16;
            int A0 = __shfl(P0, L1, 64), A1 = __shfl(P1, L1, 64);
            int A2 = __shfl(P2, L1, 64), A3 = __shfl(P3, L1, 64);
            int C0 = __shfl(P0, L2, 64), C1 = __shfl(P1, L2, 64);
            int C2 = __shfl(P2, L2, 64), C3 = __shfl(P3, L2, 64);
            const int F0 = hi ? A2 : A0, F1 = hi ? A3 : A1;
            const int F2 = hi ? C2 : C0, F3 = hi ? C3 : C1;
            short8 Gf;
            Gf[0] = (short)(F0 & 0xFFFF); Gf[1] = (short)((unsigned)F0 >> 16);
            Gf[2] = (short)(F1 & 0xFFFF); Gf[3] = (short)((unsigned)F1 >> 16);
            Gf[4] = (short)(F2 & 0xFFFF); Gf[5] = (short)((unsigned)F2 >> 16);
            Gf[6] = (short)(F3 & 0xFFFF); Gf[7] = (short)((unsigned)F3 >> 16);

            // residual: R = Wr * G (K=32), then h' = h + R + b_res
            float4v r0 = {0.f, 0.f, 0.f, 0.f}, r1 = {0.f, 0.f, 0.f, 0.f};
            r0 = __builtin_amdgcn_mfma_f32_16x16x32_bf16(WR[0], Gf, r0, 0, 0, 0);
            r1 = __builtin_amdgcn_mfma_f32_16x16x32_bf16(WR[1], Gf, r1, 0, 0, 0);

            const short4v h0 = *(const short4v*)(src + rowu * HSTR + q * 4);
            const short4v h1 = *(const short4v*)(src + rowu * HSTR + 16 + q * 4);
            short4v n0, n1;
            #pragma unroll
            for (int r = 0; r < 4; ++r) {
                n0[r] = (short)f2bf(bf2f((unsigned short)h0[r]) + r0[r] + BR[0][r]);
                n1[r] = (short)f2bf(bf2f((unsigned short)h1[r]) + r1[r] + BR[1][r]);
            }
            *(short4v*)(dst + rowu * HSTR + q * 4)      = n0;
            *(short4v*)(dst + rowu * HSTR + 16 + q * 4) = n1;
        }
        __syncthreads();
    }

    // ---- output proj: logits[t] = sum_k wo[k]*h[k][t] + bo  (final h in H0) ----
    {
        float wo[32];
        #pragma unroll
        for (int k = 0; k < 32; ++k) wo[k] = w_out[k];
        float bo = b_out[0];
        for (int t = tid; t < SEQ; t += BLK) {
            const unsigned short* hp = H0 + (PADT + t) * HSTR;
            float s = bo;
            #pragma unroll
            for (int k = 0; k < 32; ++k) s += wo[k] * bf2f(hp[k]);
            out[b * SEQ + t] = s;
        }
    }
}

extern "C" void kernel_launch(void* const* d_in, const int* in_sizes, int n_in,
                              void* d_out, int out_size, void* d_ws, size_t ws_size,
                              hipStream_t stream) {
    const float* x        = (const float*)d_in[0];
    const float* w_causal = (const float*)d_in[1];
    const float* b_causal = (const float*)d_in[2];
    const float* w_dil    = (const float*)d_in[3];
    const float* b_dil    = (const float*)d_in[4];
    const float* w_res    = (const float*)d_in[5];
    const float* b_res    = (const float*)d_in[6];
    const float* w_out    = (const float*)d_in[7];
    const float* b_out    = (const float*)d_in[8];
    float* out = (float*)d_out;

    const int B = in_sizes[0] / SEQ;  // 2048

    (void)hipFuncSetAttribute(reinterpret_cast<const void*>(wavenet_kernel),
                              hipFuncAttributeMaxDynamicSharedMemorySize, LDS_BYTES);

    wavenet_kernel<<<B, BLK, LDS_BYTES, stream>>>(
        x, w_causal, b_causal, w_dil, b_dil, w_res, b_res, w_out, b_out, out);
}